// Round 1
// baseline (69.202 us; speedup 1.0000x reference)
//
#include <hip/hip_runtime.h>

#define N_SAMPLES 64
#define M_ELEMS   307200            // 480*640 per-sample elements
#define M4        (M_ELEMS / 4)     // 76800 float4 per sample
#define BPS       32                // blocks per sample
#define BLOCK     256

__device__ __forceinline__ float wave_reduce_max(float v) {
    #pragma unroll
    for (int off = 32; off > 0; off >>= 1)
        v = fmaxf(v, __shfl_down(v, off, 64));
    return v;
}

__device__ __forceinline__ float wave_reduce_sum(float v) {
    #pragma unroll
    for (int off = 32; off > 0; off >>= 1)
        v += __shfl_down(v, off, 64);
    return v;
}

// Pass 1: per-sample max of |pred - targ|
__global__ __launch_bounds__(BLOCK) void berhu_max_kernel(
        const float* __restrict__ pred,
        const float* __restrict__ targ,
        unsigned int* __restrict__ maxbits) {
    const int n = blockIdx.y;
    const float4* p = (const float4*)(pred + (size_t)n * M_ELEMS);
    const float4* t = (const float4*)(targ + (size_t)n * M_ELEMS);

    float m = 0.0f;
    for (int i = blockIdx.x * BLOCK + threadIdx.x; i < M4; i += BPS * BLOCK) {
        float4 a = p[i];
        float4 b = t[i];
        m = fmaxf(m, fabsf(a.x - b.x));
        m = fmaxf(m, fabsf(a.y - b.y));
        m = fmaxf(m, fabsf(a.z - b.z));
        m = fmaxf(m, fabsf(a.w - b.w));
    }

    m = wave_reduce_max(m);
    __shared__ float smax[BLOCK / 64];
    const int wid  = threadIdx.x >> 6;
    const int lane = threadIdx.x & 63;
    if (lane == 0) smax[wid] = m;
    __syncthreads();
    if (threadIdx.x == 0) {
        float bm = smax[0];
        #pragma unroll
        for (int w = 1; w < BLOCK / 64; ++w) bm = fmaxf(bm, smax[w]);
        // |d| >= 0, so uint bit-pattern compare == float compare
        atomicMax(&maxbits[n], __float_as_uint(bm));
    }
}

// Pass 2: per-sample BerHu sum
__global__ __launch_bounds__(BLOCK) void berhu_sum_kernel(
        const float* __restrict__ pred,
        const float* __restrict__ targ,
        const unsigned int* __restrict__ maxbits,
        float* __restrict__ sums) {
    const int n = blockIdx.y;
    const float c = __uint_as_float(maxbits[n]) * 0.2f;   // max/5
    const float c2 = c * c;
    const float inv2c = (c > 0.0f) ? (0.5f / c) : 0.0f;

    const float4* p = (const float4*)(pred + (size_t)n * M_ELEMS);
    const float4* t = (const float4*)(targ + (size_t)n * M_ELEMS);

    float s = 0.0f;
    for (int i = blockIdx.x * BLOCK + threadIdx.x; i < M4; i += BPS * BLOCK) {
        float4 a = p[i];
        float4 b = t[i];
        float d, ad;
        d = a.x - b.x; ad = fabsf(d); s += (ad <= c) ? ad : (d * d + c2) * inv2c;
        d = a.y - b.y; ad = fabsf(d); s += (ad <= c) ? ad : (d * d + c2) * inv2c;
        d = a.z - b.z; ad = fabsf(d); s += (ad <= c) ? ad : (d * d + c2) * inv2c;
        d = a.w - b.w; ad = fabsf(d); s += (ad <= c) ? ad : (d * d + c2) * inv2c;
    }

    s = wave_reduce_sum(s);
    __shared__ float ssum[BLOCK / 64];
    const int wid  = threadIdx.x >> 6;
    const int lane = threadIdx.x & 63;
    if (lane == 0) ssum[wid] = s;
    __syncthreads();
    if (threadIdx.x == 0) {
        float bs = ssum[0];
        #pragma unroll
        for (int w = 1; w < BLOCK / 64; ++w) bs += ssum[w];
        atomicAdd(&sums[n], bs);
    }
}

// Finalize: mean over elements, mean over samples
__global__ void berhu_final_kernel(const float* __restrict__ sums,
                                   float* __restrict__ out) {
    float v = sums[threadIdx.x] * (1.0f / (float)M_ELEMS);
    v = wave_reduce_sum(v);
    if (threadIdx.x == 0) out[0] = v * (1.0f / (float)N_SAMPLES);
}

extern "C" void kernel_launch(void* const* d_in, const int* in_sizes, int n_in,
                              void* d_out, int out_size, void* d_ws, size_t ws_size,
                              hipStream_t stream) {
    const float* pred = (const float*)d_in[0];
    const float* targ = (const float*)d_in[1];
    float* out = (float*)d_out;

    unsigned int* maxbits = (unsigned int*)d_ws;
    float* sums = (float*)d_ws + N_SAMPLES;

    // ws is poisoned 0xAA and NOT re-poisoned between replays — zero it every call.
    hipMemsetAsync(d_ws, 0, 2 * N_SAMPLES * sizeof(float), stream);

    dim3 grid(BPS, N_SAMPLES);
    berhu_max_kernel<<<grid, BLOCK, 0, stream>>>(pred, targ, maxbits);
    berhu_sum_kernel<<<grid, BLOCK, 0, stream>>>(pred, targ, maxbits, sums);
    berhu_final_kernel<<<1, 64, 0, stream>>>(sums, out);
}